// Round 2
// baseline (1392.633 us; speedup 1.0000x reference)
//
#include <hip/hip_runtime.h>
#include <hip/hip_bf16.h>

typedef __bf16 bf16x8 __attribute__((ext_vector_type(8)));
typedef float floatx4 __attribute__((ext_vector_type(4)));

constexpr int M_NODES = 50000;
constexpr int HSZ  = 256;
constexpr int KDIM = 1536;   // 256 (x part) + 1280 (h_flat part)
constexpr int NDIM = 2048;   // 8 gates (f0..f4, i, o, u) * 256
constexpr int BM = 128, BN = 128, BK = 32, LDK = 40;  // +8 pad: 80B row stride, 16B aligned
constexpr int MT = (M_NODES + BM - 1) / BM;  // 391
constexpr int NT = NDIM / BN;                // 16

// Build bf16 WcT[n][k] (N-major: B-fragment reads are contiguous-K ds_read_b128).
// n = tb*128 + s*16 + tl; gate s: 0..4 = f_child_s, 5=i, 6=o, 7=u; t = tb*16+tl.
// x-rows (k<256) of f columns carry 2*W_f_in (reference adds f_input twice).
__global__ __launch_bounds__(256) void prep_weights(
    const float* __restrict__ W_iou_in, const float* __restrict__ W_f_in,
    const float* __restrict__ W_aggr_iou, const float* __restrict__ W_aggr_f,
    __bf16* __restrict__ WcT)
{
  int idx = blockIdx.x * 256 + threadIdx.x;
  if (idx >= NDIM * KDIM) return;
  int n = idx / KDIM, k = idx - n * KDIM;
  int tb = n >> 7, rem = n & 127;
  int s = rem >> 4, tl = rem & 15;
  int t = tb * 16 + tl;
  float v;
  if (k < 256) {
    if (s < 5) v = 2.0f * W_f_in[k * 256 + t];
    else       v = W_iou_in[k * 768 + (s - 5) * 256 + t];
  } else {
    int kh = k - 256;
    if (s < 5) v = W_aggr_f[kh * 1280 + s * 256 + t];
    else       v = W_aggr_iou[kh * 768 + (s - 5) * 256 + t];
  }
  WcT[idx] = (__bf16)v;
}

__device__ __forceinline__ float sigm(float v) { return 1.0f / (1.0f + __expf(-v)); }
__device__ __forceinline__ float tanh_(float v) { return 2.0f / (1.0f + __expf(-2.0f * v)) - 1.0f; }

__global__ __launch_bounds__(256) void fused_treelstm(
    const float* __restrict__ x, const float* __restrict__ xmask,
    const float* __restrict__ nh, const float* __restrict__ nc,
    const float* __restrict__ b_iou, const float* __restrict__ b_f,
    const float* __restrict__ b_aiou, const float* __restrict__ b_af,
    const __bf16* __restrict__ WcT, float* __restrict__ out)
{
  __shared__ __bf16 ldsA[BM * LDK];
  __shared__ __bf16 ldsB[BN * LDK];

  const int tid = threadIdx.x;
  const int bn = blockIdx.x;          // n-tile: 16 t-values, all 8 gates
  const int m0 = blockIdx.y * BM;

  // staging: thread -> row (tid>>1), two 8-element k-chunks
  const int srow = tid >> 1;
  const int kc0  = tid & 1;
  const int arow_g = m0 + srow;
  const int arow_c = arow_g < M_NODES ? arow_g : M_NODES - 1;  // tail clamp (stores guarded)
  const float xm_stage = xmask[arow_c];
  const float* aptr_x = x  + (size_t)arow_c * 256;
  const float* aptr_h = nh + (size_t)arow_c * 1280 - 256;      // indexed by kg >= 256
  const __bf16* bptr  = WcT + (size_t)(bn * BN + srow) * KDIM;

  const int lane = tid & 63;
  const int w    = tid >> 6;           // wave w owns D-rows w*32..w*32+31, all 128 cols
  const int frow = lane & 15;
  const int kq   = lane >> 4;

  floatx4 acc[2][8];
#pragma unroll
  for (int mt = 0; mt < 2; ++mt)
#pragma unroll
    for (int nt = 0; nt < 8; ++nt) acc[mt][nt] = (floatx4)(0.0f);

  for (int kt = 0; kt < KDIM / BK; ++kt) {
    const int k0 = kt * BK;
    __syncthreads();
#pragma unroll
    for (int i = 0; i < 2; ++i) {
      const int kl = (kc0 + 2 * i) * 8;
      const int kg = k0 + kl;
      const float* src = (kg < 256) ? (aptr_x + kg) : (aptr_h + kg);
      const float scale = (kg < 256) ? xm_stage : 1.0f;
      float4 f0 = *(const float4*)(src);
      float4 f1 = *(const float4*)(src + 4);
      bf16x8 va;
      va[0] = (__bf16)(f0.x * scale); va[1] = (__bf16)(f0.y * scale);
      va[2] = (__bf16)(f0.z * scale); va[3] = (__bf16)(f0.w * scale);
      va[4] = (__bf16)(f1.x * scale); va[5] = (__bf16)(f1.y * scale);
      va[6] = (__bf16)(f1.z * scale); va[7] = (__bf16)(f1.w * scale);
      *(bf16x8*)(&ldsA[srow * LDK + kl]) = va;
      bf16x8 vb = *(const bf16x8*)(bptr + kg);
      *(bf16x8*)(&ldsB[srow * LDK + kl]) = vb;
    }
    __syncthreads();
    bf16x8 a0 = *(const bf16x8*)&ldsA[(w * 32 + frow) * LDK + kq * 8];
    bf16x8 a1 = *(const bf16x8*)&ldsA[(w * 32 + 16 + frow) * LDK + kq * 8];
#pragma unroll
    for (int nt = 0; nt < 8; ++nt) {
      bf16x8 b = *(const bf16x8*)&ldsB[(nt * 16 + frow) * LDK + kq * 8];
      acc[0][nt] = __builtin_amdgcn_mfma_f32_16x16x32_bf16(a0, b, acc[0][nt], 0, 0, 0);
      acc[1][nt] = __builtin_amdgcn_mfma_f32_16x16x32_bf16(a1, b, acc[1][nt], 0, 0, 0);
    }
  }

  // register-local epilogue: acc[mt][s][j] holds gate s for row r, column t
  const int t = bn * 16 + frow;
  float baf5[5];
#pragma unroll
  for (int s = 0; s < 5; ++s) baf5[s] = b_af[s * 256 + t];
  const float bf2 = 2.0f * b_f[t];
  float biou3[3], baiou3[3];
#pragma unroll
  for (int g = 0; g < 3; ++g) {
    biou3[g]  = b_iou[g * 256 + t];
    baiou3[g] = b_aiou[g * 256 + t];
  }

#pragma unroll
  for (int mt = 0; mt < 2; ++mt) {
#pragma unroll
    for (int j = 0; j < 4; ++j) {
      const int r = m0 + w * 32 + mt * 16 + kq * 4 + j;
      if (r >= M_NODES) continue;
      const float mk = xmask[r];
      float ca = 0.0f;
#pragma unroll
      for (int s = 0; s < 5; ++s) {
        const float fa = acc[mt][s][j] + baf5[s] + mk * bf2;
        ca += sigm(fa) * nc[((size_t)r * 5 + s) * 256 + t];
      }
      const float iv = sigm(acc[mt][5][j] + mk * biou3[0] + baiou3[0]);
      const float ov = sigm(acc[mt][6][j] + mk * biou3[1] + baiou3[1]);
      const float uv = tanh_(acc[mt][7][j] + mk * biou3[2] + baiou3[2]);
      const float c  = iv * uv + ca;
      const float h  = ov * tanh_(c);
      out[(size_t)r * HSZ + t] = h;
      out[(size_t)M_NODES * HSZ + (size_t)r * HSZ + t] = c;
    }
  }
}

extern "C" void kernel_launch(void* const* d_in, const int* in_sizes, int n_in,
                              void* d_out, int out_size, void* d_ws, size_t ws_size,
                              hipStream_t stream)
{
  const float* x      = (const float*)d_in[0];
  const float* xmask  = (const float*)d_in[1];
  const float* nh     = (const float*)d_in[2];
  const float* nc     = (const float*)d_in[3];
  const float* W_iou  = (const float*)d_in[4];
  const float* b_iou  = (const float*)d_in[5];
  const float* W_f    = (const float*)d_in[6];
  const float* b_f    = (const float*)d_in[7];
  const float* W_aiou = (const float*)d_in[8];
  const float* b_aiou = (const float*)d_in[9];
  const float* W_af   = (const float*)d_in[10];
  const float* b_af   = (const float*)d_in[11];
  __bf16* WcT = (__bf16*)d_ws;   // 2048*1536*2 B = 6.29 MB, rebuilt every call
  float* out  = (float*)d_out;

  prep_weights<<<(NDIM * KDIM + 255) / 256, 256, 0, stream>>>(W_iou, W_f, W_aiou, W_af, WcT);
  fused_treelstm<<<dim3(NT, MT), 256, 0, stream>>>(x, xmask, nh, nc, b_iou, b_f, b_aiou, b_af, WcT, out);
}

// Round 3
// 1116.597 us; speedup vs baseline: 1.2472x; 1.2472x over previous
//
#include <hip/hip_runtime.h>
#include <hip/hip_bf16.h>

typedef __bf16 bf16x8 __attribute__((ext_vector_type(8)));
typedef float floatx4 __attribute__((ext_vector_type(4)));

#define GLOBAL_AS __attribute__((address_space(1)))
#define LDS_AS __attribute__((address_space(3)))

constexpr int M_NODES = 50000;
constexpr int HSZ  = 256;
constexpr int KDIM = 1536;   // 256 (x part) + 1280 (h_flat part)
constexpr int NDIM = 2048;   // 8 gates (f0..f4, i, o, u) * 256
constexpr int BM = 128, BN = 128, BK = 32;
constexpr int MT = (M_NODES + BM - 1) / BM;  // 391
constexpr int NT = NDIM / BN;                // 16
constexpr size_t WCT_BYTES = (size_t)NDIM * KDIM * 2;       // 6.29 MB
constexpr size_t A_BYTES   = (size_t)M_NODES * KDIM * 2;    // 153.6 MB

// ---------------- weight fusion: bf16 WcT[n][k], N-major ----------------
// n = tb*128 + s*16 + tl; gate s: 0..4 = f_child_s, 5=i, 6=o, 7=u; t = tb*16+tl.
// x-rows (k<256) of f columns carry 2*W_f_in (reference adds f_input twice).
__global__ __launch_bounds__(256) void prep_weights(
    const float* __restrict__ W_iou_in, const float* __restrict__ W_f_in,
    const float* __restrict__ W_aggr_iou, const float* __restrict__ W_aggr_f,
    __bf16* __restrict__ WcT)
{
  int idx = blockIdx.x * 256 + threadIdx.x;
  if (idx >= NDIM * KDIM) return;
  int n = idx / KDIM, k = idx - n * KDIM;
  int tb = n >> 7, rem = n & 127;
  int s = rem >> 4, tl = rem & 15;
  int t = tb * 16 + tl;
  float v;
  if (k < 256) {
    if (s < 5) v = 2.0f * W_f_in[k * 256 + t];
    else       v = W_iou_in[k * 768 + (s - 5) * 256 + t];
  } else {
    int kh = k - 256;
    if (s < 5) v = W_aggr_f[kh * 1280 + s * 256 + t];
    else       v = W_aggr_iou[kh * 768 + (s - 5) * 256 + t];
  }
  WcT[idx] = (__bf16)v;
}

// ---------------- A fusion: bf16 Abf[r][0:256]=x*mask, [256:1536]=nh ----------------
__global__ __launch_bounds__(256) void prep_A(
    const float* __restrict__ x, const float* __restrict__ xmask,
    const float* __restrict__ nh, __bf16* __restrict__ Abf)
{
  int ci = blockIdx.x * 256 + threadIdx.x;       // one 8-element chunk
  if (ci >= M_NODES * (KDIM / 8)) return;
  int row = ci / (KDIM / 8);
  int kc  = ci - row * (KDIM / 8);
  const float* src;
  float sc;
  if (kc < 32) { src = x  + (size_t)row * 256  + kc * 8;        sc = xmask[row]; }
  else         { src = nh + (size_t)row * 1280 + (size_t)(kc - 32) * 8; sc = 1.0f; }
  float4 f0 = *(const float4*)src;
  float4 f1 = *(const float4*)(src + 4);
  bf16x8 v;
  v[0] = (__bf16)(f0.x * sc); v[1] = (__bf16)(f0.y * sc);
  v[2] = (__bf16)(f0.z * sc); v[3] = (__bf16)(f0.w * sc);
  v[4] = (__bf16)(f1.x * sc); v[5] = (__bf16)(f1.y * sc);
  v[6] = (__bf16)(f1.z * sc); v[7] = (__bf16)(f1.w * sc);
  *(bf16x8*)(Abf + (size_t)row * KDIM + kc * 8) = v;
}

__device__ __forceinline__ float sigm(float v) { return 1.0f / (1.0f + __expf(-v)); }
__device__ __forceinline__ float tanh_(float v) { return 2.0f / (1.0f + __expf(-2.0f * v)) - 1.0f; }

// ---------------- main GEMM + LSTM epilogue, m97-style staging ----------------
// LDS tile layout (A and B identical): 128 rows x 4 chunks of 8 bf16 (16 B), unpadded.
// Swizzle: chunk c of row r lives at slot c ^ ((r>>1)&3)  -> fragment reads are
// 2-way-per-bank-group (free). global_load_lds stores: lane l of issue j holds
// row 16j+(l>>2), slot l&3, i.e. logical chunk (l&3)^((l>>3)&3) -- lane-constant.
__global__ __launch_bounds__(256) void gemm_treelstm(
    const __bf16* __restrict__ Abf, const __bf16* __restrict__ WcT,
    const float* __restrict__ xmask, const float* __restrict__ nc,
    const float* __restrict__ b_iou, const float* __restrict__ b_f,
    const float* __restrict__ b_aiou, const float* __restrict__ b_af,
    float* __restrict__ out)
{
  __shared__ __bf16 ldsA[BM * BK];   // 8 KB
  __shared__ __bf16 ldsB[BN * BK];   // 8 KB

  const int tid = threadIdx.x;
  const int bn  = blockIdx.x;        // n-tile: 16 t-values, all 8 gates
  const int m0  = blockIdx.y * BM;

  const int lane = tid & 63;
  const int w    = tid >> 6;         // wave: owns D-rows w*32..w*32+31, all 128 cols
  const int frow = lane & 15;
  const int kq   = lane >> 4;

  // ---- staging addresses (global_load_lds), lane-constant ----
  const int lrow = lane >> 2;                       // 0..15
  const int cch  = (lane & 3) ^ ((lane >> 3) & 3);  // logical chunk for this lane's slot
  const int ar0  = m0 + w * 32 + lrow;
  const int ar1  = ar0 + 16;
  const __bf16* pA0 = Abf + (size_t)(ar0 < M_NODES ? ar0 : M_NODES - 1) * KDIM + cch * 8;
  const __bf16* pA1 = Abf + (size_t)(ar1 < M_NODES ? ar1 : M_NODES - 1) * KDIM + cch * 8;
  const __bf16* pB0 = WcT + (size_t)(bn * BN + w * 32 + lrow) * KDIM + cch * 8;
  const __bf16* pB1 = pB0 + (size_t)16 * KDIM;

  // ---- fragment read offsets (elements), swizzled ----
  const int flane = ((kq ^ ((frow >> 1) & 3)) * 8);
  const int aoff0 = (w * 32 + frow) * BK + flane;
  const int aoff1 = aoff0 + 16 * BK;
  const int boff  = frow * BK + flane;

  floatx4 acc[2][8];
#pragma unroll
  for (int mt = 0; mt < 2; ++mt)
#pragma unroll
    for (int nt = 0; nt < 8; ++nt) acc[mt][nt] = (floatx4)(0.0f);

  for (int kt = 0; kt < KDIM / BK; ++kt) {
    __syncthreads();
    __builtin_amdgcn_global_load_lds((const GLOBAL_AS void*)pA0,
        (LDS_AS void*)((LDS_AS char*)(LDS_AS __bf16*)ldsA + (2 * w + 0) * 1024), 16, 0, 0);
    __builtin_amdgcn_global_load_lds((const GLOBAL_AS void*)pA1,
        (LDS_AS void*)((LDS_AS char*)(LDS_AS __bf16*)ldsA + (2 * w + 1) * 1024), 16, 0, 0);
    __builtin_amdgcn_global_load_lds((const GLOBAL_AS void*)pB0,
        (LDS_AS void*)((LDS_AS char*)(LDS_AS __bf16*)ldsB + (2 * w + 0) * 1024), 16, 0, 0);
    __builtin_amdgcn_global_load_lds((const GLOBAL_AS void*)pB1,
        (LDS_AS void*)((LDS_AS char*)(LDS_AS __bf16*)ldsB + (2 * w + 1) * 1024), 16, 0, 0);
    pA0 += BK; pA1 += BK; pB0 += BK; pB1 += BK;
    __syncthreads();

    bf16x8 a0 = *(const bf16x8*)&ldsA[aoff0];
    bf16x8 a1 = *(const bf16x8*)&ldsA[aoff1];
#pragma unroll
    for (int nt = 0; nt < 8; ++nt) {
      bf16x8 b = *(const bf16x8*)&ldsB[boff + nt * 512];
      acc[0][nt] = __builtin_amdgcn_mfma_f32_16x16x32_bf16(a0, b, acc[0][nt], 0, 0, 0);
      acc[1][nt] = __builtin_amdgcn_mfma_f32_16x16x32_bf16(a1, b, acc[1][nt], 0, 0, 0);
    }
  }

  // ---- register-local epilogue: acc[mt][s][j] = gate s, row r, column t ----
  const int t = bn * 16 + frow;
  float baf5[5];
#pragma unroll
  for (int s = 0; s < 5; ++s) baf5[s] = b_af[s * 256 + t];
  const float bf2 = 2.0f * b_f[t];
  float biou3[3], baiou3[3];
#pragma unroll
  for (int g = 0; g < 3; ++g) {
    biou3[g]  = b_iou[g * 256 + t];
    baiou3[g] = b_aiou[g * 256 + t];
  }

#pragma unroll
  for (int mt = 0; mt < 2; ++mt) {
#pragma unroll
    for (int j = 0; j < 4; ++j) {
      const int r = m0 + w * 32 + mt * 16 + kq * 4 + j;
      if (r >= M_NODES) continue;
      const float mk = xmask[r];
      float ca = 0.0f;
#pragma unroll
      for (int s = 0; s < 5; ++s) {
        const float fa = acc[mt][s][j] + baf5[s] + mk * bf2;
        ca += sigm(fa) * nc[((size_t)r * 5 + s) * 256 + t];
      }
      const float iv = sigm(acc[mt][5][j] + mk * biou3[0] + baiou3[0]);
      const float ov = sigm(acc[mt][6][j] + mk * biou3[1] + baiou3[1]);
      const float uv = tanh_(acc[mt][7][j] + mk * biou3[2] + baiou3[2]);
      const float c  = iv * uv + ca;
      const float h  = ov * tanh_(c);
      out[(size_t)r * HSZ + t] = h;
      out[(size_t)M_NODES * HSZ + (size_t)r * HSZ + t] = c;
    }
  }
}

// ---------------- fallback (round-2 kernel) if ws too small for Abf ----------------
constexpr int LDKF = 40;
__global__ __launch_bounds__(256) void fused_treelstm_fb(
    const float* __restrict__ x, const float* __restrict__ xmask,
    const float* __restrict__ nh, const float* __restrict__ nc,
    const float* __restrict__ b_iou, const float* __restrict__ b_f,
    const float* __restrict__ b_aiou, const float* __restrict__ b_af,
    const __bf16* __restrict__ WcT, float* __restrict__ out)
{
  __shared__ __bf16 ldsA[BM * LDKF];
  __shared__ __bf16 ldsB[BN * LDKF];
  const int tid = threadIdx.x;
  const int bn = blockIdx.x;
  const int m0 = blockIdx.y * BM;
  const int srow = tid >> 1;
  const int kc0  = tid & 1;
  const int arow_g = m0 + srow;
  const int arow_c = arow_g < M_NODES ? arow_g : M_NODES - 1;
  const float xm_stage = xmask[arow_c];
  const float* aptr_x = x  + (size_t)arow_c * 256;
  const float* aptr_h = nh + (size_t)arow_c * 1280 - 256;
  const __bf16* bptr  = WcT + (size_t)(bn * BN + srow) * KDIM;
  const int lane = tid & 63;
  const int w    = tid >> 6;
  const int frow = lane & 15;
  const int kq   = lane >> 4;
  floatx4 acc[2][8];
#pragma unroll
  for (int mt = 0; mt < 2; ++mt)
#pragma unroll
    for (int nt = 0; nt < 8; ++nt) acc[mt][nt] = (floatx4)(0.0f);
  for (int kt = 0; kt < KDIM / BK; ++kt) {
    const int k0 = kt * BK;
    __syncthreads();
#pragma unroll
    for (int i = 0; i < 2; ++i) {
      const int kl = (kc0 + 2 * i) * 8;
      const int kg = k0 + kl;
      const float* src = (kg < 256) ? (aptr_x + kg) : (aptr_h + kg);
      const float scale = (kg < 256) ? xm_stage : 1.0f;
      float4 f0 = *(const float4*)(src);
      float4 f1 = *(const float4*)(src + 4);
      bf16x8 va;
      va[0] = (__bf16)(f0.x * scale); va[1] = (__bf16)(f0.y * scale);
      va[2] = (__bf16)(f0.z * scale); va[3] = (__bf16)(f0.w * scale);
      va[4] = (__bf16)(f1.x * scale); va[5] = (__bf16)(f1.y * scale);
      va[6] = (__bf16)(f1.z * scale); va[7] = (__bf16)(f1.w * scale);
      *(bf16x8*)(&ldsA[srow * LDKF + kl]) = va;
      bf16x8 vb = *(const bf16x8*)(bptr + kg);
      *(bf16x8*)(&ldsB[srow * LDKF + kl]) = vb;
    }
    __syncthreads();
    bf16x8 a0 = *(const bf16x8*)&ldsA[(w * 32 + frow) * LDKF + kq * 8];
    bf16x8 a1 = *(const bf16x8*)&ldsA[(w * 32 + 16 + frow) * LDKF + kq * 8];
#pragma unroll
    for (int nt = 0; nt < 8; ++nt) {
      bf16x8 b = *(const bf16x8*)&ldsB[(nt * 16 + frow) * LDKF + kq * 8];
      acc[0][nt] = __builtin_amdgcn_mfma_f32_16x16x32_bf16(a0, b, acc[0][nt], 0, 0, 0);
      acc[1][nt] = __builtin_amdgcn_mfma_f32_16x16x32_bf16(a1, b, acc[1][nt], 0, 0, 0);
    }
  }
  const int t = bn * 16 + frow;
  float baf5[5];
#pragma unroll
  for (int s = 0; s < 5; ++s) baf5[s] = b_af[s * 256 + t];
  const float bf2 = 2.0f * b_f[t];
  float biou3[3], baiou3[3];
#pragma unroll
  for (int g = 0; g < 3; ++g) {
    biou3[g]  = b_iou[g * 256 + t];
    baiou3[g] = b_aiou[g * 256 + t];
  }
#pragma unroll
  for (int mt = 0; mt < 2; ++mt) {
#pragma unroll
    for (int j = 0; j < 4; ++j) {
      const int r = m0 + w * 32 + mt * 16 + kq * 4 + j;
      if (r >= M_NODES) continue;
      const float mk = xmask[r];
      float ca = 0.0f;
#pragma unroll
      for (int s = 0; s < 5; ++s) {
        const float fa = acc[mt][s][j] + baf5[s] + mk * bf2;
        ca += sigm(fa) * nc[((size_t)r * 5 + s) * 256 + t];
      }
      const float iv = sigm(acc[mt][5][j] + mk * biou3[0] + baiou3[0]);
      const float ov = sigm(acc[mt][6][j] + mk * biou3[1] + baiou3[1]);
      const float uv = tanh_(acc[mt][7][j] + mk * biou3[2] + baiou3[2]);
      const float c  = iv * uv + ca;
      const float h  = ov * tanh_(c);
      out[(size_t)r * HSZ + t] = h;
      out[(size_t)M_NODES * HSZ + (size_t)r * HSZ + t] = c;
    }
  }
}

extern "C" void kernel_launch(void* const* d_in, const int* in_sizes, int n_in,
                              void* d_out, int out_size, void* d_ws, size_t ws_size,
                              hipStream_t stream)
{
  const float* x      = (const float*)d_in[0];
  const float* xmask  = (const float*)d_in[1];
  const float* nh     = (const float*)d_in[2];
  const float* nc     = (const float*)d_in[3];
  const float* W_iou  = (const float*)d_in[4];
  const float* b_iou  = (const float*)d_in[5];
  const float* W_f    = (const float*)d_in[6];
  const float* b_f    = (const float*)d_in[7];
  const float* W_aiou = (const float*)d_in[8];
  const float* b_aiou = (const float*)d_in[9];
  const float* W_af   = (const float*)d_in[10];
  const float* b_af   = (const float*)d_in[11];
  __bf16* WcT = (__bf16*)d_ws;
  float* out  = (float*)d_out;

  prep_weights<<<(NDIM * KDIM + 255) / 256, 256, 0, stream>>>(W_iou, W_f, W_aiou, W_af, WcT);

  if (ws_size >= WCT_BYTES + A_BYTES) {
    __bf16* Abf = (__bf16*)((char*)d_ws + WCT_BYTES);
    prep_A<<<(M_NODES * (KDIM / 8) + 255) / 256, 256, 0, stream>>>(x, xmask, nh, Abf);
    gemm_treelstm<<<dim3(NT, MT), 256, 0, stream>>>(Abf, WcT, xmask, nc,
                                                    b_iou, b_f, b_aiou, b_af, out);
  } else {
    fused_treelstm_fb<<<dim3(NT, MT), 256, 0, stream>>>(x, xmask, nh, nc,
                                                        b_iou, b_f, b_aiou, b_af, WcT, out);
  }
}